// Round 9
// baseline (664.547 us; speedup 1.0000x reference)
//
#include <hip/hip_runtime.h>
#include <hip/hip_bf16.h>
#include <stdint.h>

typedef __attribute__((ext_vector_type(8))) __bf16 bf16x8;
typedef __attribute__((ext_vector_type(4))) float f32x4;

#define IN_F   4096
#define OUT_F  4096
#define M_ROWS 16384   // 8 * 2048

static __device__ __forceinline__ unsigned short f2bf(float f) {
    unsigned int u = __float_as_uint(f);
    u += 0x7FFFu + ((u >> 16) & 1u);   // round-to-nearest-even
    return (unsigned short)(u >> 16);
}

// ---------------------------------------------------------------------------
// Kernel 1: fused prep (build bf16 weight; convert x to bf16).
// ---------------------------------------------------------------------------
#define PREP_WBLK 1366
#define PREP_NBLK 4096

__global__ __launch_bounds__(256) void prep_kernel(
    const float* __restrict__ weight, const float* __restrict__ leafs,
    const float* __restrict__ x,
    unsigned short* __restrict__ wb, unsigned short* __restrict__ xbuf)
{
    const int t = threadIdx.x;
    if (blockIdx.x < PREP_WBLK) {
        __shared__ float s[4][8][8];
        {
            const int o = t >> 6, a = (t >> 3) & 7, b = t & 7;
            float acc = 0.f;
            #pragma unroll
            for (int r = 0; r < 8; ++r)
                acc += leafs[o * 512 + r * 64 + a * 8 + b];
            s[o][a][b] = acc;
        }
        __syncthreads();

        const int total = (OUT_F * IN_F) / 8;
        for (int idx = blockIdx.x * 256 + t; idx < total; idx += PREP_WBLK * 256) {
            const int n  = idx >> 9;
            const int kg = idx & 511;
            const int n0 = n >> 9, n1 = (n >> 6) & 7, n2 = (n >> 3) & 7, n3 = n & 7;
            const int k0 = kg >> 6, k1 = (kg >> 3) & 7, k2 = kg & 7;
            const float p = s[0][k0][n0] * s[1][k1][n1] * s[2][k2][n2];
            const float4* wp = (const float4*)(weight + (size_t)n * IN_F + kg * 8);
            const float4 w0 = wp[0], w1 = wp[1];
            const float wv[8] = {w0.x, w0.y, w0.z, w0.w, w1.x, w1.y, w1.z, w1.w};
            unsigned int pk[4];
            #pragma unroll
            for (int j = 0; j < 4; ++j) {
                unsigned int lo = f2bf(wv[2*j]   + p * s[3][2*j]  [n3]);
                unsigned int hi = f2bf(wv[2*j+1] + p * s[3][2*j+1][n3]);
                pk[j] = lo | (hi << 16);
            }
            *reinterpret_cast<uint4*>(wb + (size_t)n * IN_F + kg * 8) =
                make_uint4(pk[0], pk[1], pk[2], pk[3]);
        }
    } else {
        const long long n8 = (long long)M_ROWS * IN_F / 8;
        const int xblocks = PREP_NBLK - PREP_WBLK;
        for (long long idx = (long long)(blockIdx.x - PREP_WBLK) * 256 + t;
             idx < n8; idx += (long long)xblocks * 256) {
            const float4* xp = (const float4*)(x + idx * 8);
            const float4 a = xp[0], b = xp[1];
            const float v[8] = {a.x, a.y, a.z, a.w, b.x, b.y, b.z, b.w};
            unsigned int pk[4];
            #pragma unroll
            for (int j = 0; j < 4; ++j)
                pk[j] = (unsigned int)f2bf(v[2*j]) | ((unsigned int)f2bf(v[2*j+1]) << 16);
            *reinterpret_cast<uint4*>(xbuf + idx * 8) =
                make_uint4(pk[0], pk[1], pk[2], pk[3]);
        }
    }
}

// ---------------------------------------------------------------------------
// Kernel 2: 256x128 GEMM tile, BK=32, 16x16x32 MFMA, 2 blocks/CU (TLP).
//
// 512 thr = 8 waves (4M x 2N); wave tile 64x64 -> acc[4][4] f32x4 = 64 regs.
// __launch_bounds__(512, 4) caps total regs at 128 -> 16 waves/CU -> two
// blocks drift out of phase and overlap LDS-pipe with MFMA-pipe (m97/m114
// mechanism), which 5 rounds of intra-block scheduling could not achieve.
//
// LDS 48 KB: buf P at P*24576: A [256 rows][64 B] at +0 (16 KB),
//   B [128 rows][64 B] at +16384 (8 KB).
// Element (row,col): byte row*64 + ((col*2) ^ ((row&6)<<3))  [R3: 0 confl].
// Staged linearly by global_load_lds from inverse-swizzled global sources:
//   3 GLLs/thread/tile (A rows 0-127, A rows 128-255, B rows 0-127).
//
// Per tile (buf P): { issue 3 GLL -> buf P^1; 8 ds_reads (A m0-3, B n0-3);
//   lgkm(0); setprio(1); 16 MFMA; setprio(0); vmcnt(0); BAR }.
// Hazards: all waves drain lgkm before BAR, so buf P^1's GLLs (issued after
// the previous BAR) never overwrite data still being read; vmcnt(0) at tile
// end guarantees buf P^1 is complete before any wave reads it next tile.
// ---------------------------------------------------------------------------
#define BK2   32
#define NT2   128
#define BUFSZ 24576

#define GLL(src, dst) __builtin_amdgcn_global_load_lds( \
    (const __attribute__((address_space(1))) void*)(src), \
    (__attribute__((address_space(3))) void*)(dst), 16, 0, 0)

#define SB0  __builtin_amdgcn_sched_barrier(0)
#define BAR  __builtin_amdgcn_s_barrier()
#define PRI1 __builtin_amdgcn_s_setprio(1)
#define PRI0 __builtin_amdgcn_s_setprio(0)
#define WLG0 asm volatile("s_waitcnt lgkmcnt(0)" ::: "memory")
#define WVM0 asm volatile("s_waitcnt vmcnt(0)" ::: "memory")

#define STAGE2(P, KO) do { \
    GLL(sA1 + (KO), ldsb + (P)*BUFSZ + d1); \
    GLL(sA2 + (KO), ldsb + (P)*BUFSZ + 8192 + d1); \
    GLL(sBp + (KO), ldsb + (P)*BUFSZ + 16384 + d1); } while (0)

__global__ __launch_bounds__(512, 4) void gemm_tlp_kernel(
    const unsigned short* __restrict__ xb,   // bf16 x [M_ROWS][IN_F]
    const unsigned short* __restrict__ wb,   // bf16 W [OUT_F][IN_F]
    const float* __restrict__ bias,
    float* __restrict__ out)
{
    __shared__ unsigned short lds_us[24576];   // 48 KiB
    char* const ldsb = (char*)lds_us;

    const int t    = threadIdx.x;
    const int wave = t >> 6;
    const int lane = t & 63;
    const int lr   = lane & 15;
    const int kq   = lane >> 4;
    const int wr   = wave >> 1;      // 0..3  (M)
    const int wcn  = wave & 1;       // 0..1  (N)
    const int sx   = (lr & 6) << 3;

    // bijective XCD swizzle (2048 blocks); 8 bm-groups x 32 bn per XCD chunk,
    // bn-major so each XCD's 2048-row A slice stays L2-hot within a K-step.
    const int bid  = blockIdx.x;
    const int swzb = (bid & 7) * 256 + (bid >> 3);
    const int bm   = (swzb >> 5) * 256;   // 64 M-tiles
    const int bn   = (swzb & 31) * 128;   // 32 N-tiles

    // staging: thread t owns 16B chunks at d1, d1+8192 (A) and d1 (B region)
    const int rA = t >> 2;                               // 0..127
    const int q  = ((t & 3) * 16) ^ ((rA & 6) << 3);     // inv-swizzled src byte
    const unsigned short* sA1 = xb + (size_t)(bm + rA) * IN_F + (q >> 1);
    const unsigned short* sA2 = sA1 + (size_t)128 * IN_F;   // rows 128-255
    const unsigned short* sBp = wb + (size_t)(bn + rA) * IN_F + (q >> 1);
    const int d1 = t * 16;

    // per-lane read bases (swizzled); fragment m/n offsets are +m*1024
    const char* aBase = ldsb + (wr * 64 + lr) * 64 + ((kq * 16) ^ sx);
    const char* bBase = ldsb + 16384 + (wcn * 64 + lr) * 64 + ((kq * 16) ^ sx);

    f32x4 acc[4][4] = {};

    // prologue: stage tile 0 into buf 0, drain, sync.
    STAGE2(0, 0);
    WVM0; BAR;

    #pragma unroll 1
    for (int tt = 0; tt < NT2; ++tt) {
        const int P = tt & 1;
        const bool pf = (tt + 1 < NT2);
        if (pf) STAGE2(P ^ 1, (tt + 1) * BK2);

        bf16x8 aS[4], bS[4];
        #pragma unroll
        for (int m = 0; m < 4; ++m)
            aS[m] = *(const bf16x8*)(aBase + P * BUFSZ + m * 1024);
        #pragma unroll
        for (int n = 0; n < 4; ++n)
            bS[n] = *(const bf16x8*)(bBase + P * BUFSZ + n * 1024);

        SB0; WLG0; SB0;
        PRI1;
        #pragma unroll
        for (int m = 0; m < 4; ++m)
            #pragma unroll
            for (int n = 0; n < 4; ++n)
                acc[m][n] = __builtin_amdgcn_mfma_f32_16x16x32_bf16(
                    aS[m], bS[n], acc[m][n], 0, 0, 0);
        PRI0; SB0;
        if (pf) WVM0;
        BAR; SB0;
    }

    // ---- epilogue: C/D layout col=lr, row=kq*4+j ----
    #pragma unroll
    for (int n = 0; n < 4; ++n) {
        const int col = bn + wcn * 64 + n * 16 + lr;
        const float bv = bias[col];
        #pragma unroll
        for (int m = 0; m < 4; ++m) {
            const size_t rb = (size_t)(bm + wr * 64 + m * 16 + kq * 4) * OUT_F + col;
            #pragma unroll
            for (int j = 0; j < 4; ++j)
                out[rb + (size_t)j * OUT_F] = acc[m][n][j] + bv;
        }
    }
}

// ---------------------------------------------------------------------------
// Fallback GEMM (round-1 structure) for small workspace.
// ---------------------------------------------------------------------------
#define FBM 128
#define FBN 128
#define FBK 32

__global__ __launch_bounds__(256) void gemm_fb_kernel(
    const float* __restrict__ xf,
    const unsigned short* __restrict__ wb,
    const float* __restrict__ bias,
    float* __restrict__ out)
{
    __shared__ unsigned short As[FBM * FBK];
    __shared__ unsigned short Bs[FBN * FBK];

    const int t    = threadIdx.x;
    const int wave = t >> 6;
    const int lane = t & 63;
    const int lr   = lane & 15;
    const int kq   = lane >> 4;
    const int wr   = wave >> 1;
    const int wc   = wave & 1;

    const int bm = blockIdx.x * FBM;
    const int bn = blockIdx.y * FBN;
    const int srow = t >> 2;
    const int scol = (t & 3) * 8;

    f32x4 acc[4][4] = {};

    for (int kt = 0; kt < IN_F; kt += FBK) {
        #pragma unroll
        for (int g = 0; g < 2; ++g) {
            const int row = srow + g * 64;
            const float4* xp = (const float4*)(xf + (size_t)(bm + row) * IN_F + kt + scol);
            const float4 a0 = xp[0], a1 = xp[1];
            const float v[8] = {a0.x, a0.y, a0.z, a0.w, a1.x, a1.y, a1.z, a1.w};
            unsigned int pk[4];
            #pragma unroll
            for (int j = 0; j < 4; ++j)
                pk[j] = (unsigned int)f2bf(v[2*j]) | ((unsigned int)f2bf(v[2*j+1]) << 16);
            *reinterpret_cast<uint4*>(&As[row * FBK + scol]) =
                make_uint4(pk[0], pk[1], pk[2], pk[3]);
        }
        {
            const unsigned short* gb0 = wb + (size_t)(bn + srow) * IN_F + kt + scol;
            const unsigned short* gb1 = gb0 + (size_t)64 * IN_F;
            GLL(gb0, Bs + srow * FBK + scol);
            GLL(gb1, Bs + (64 + srow) * FBK + scol);
        }
        __syncthreads();

        bf16x8 af[4], bfr[4];
        #pragma unroll
        for (int m = 0; m < 4; ++m)
            af[m] = *reinterpret_cast<const bf16x8*>(As + (wr * 64 + m * 16 + lr) * FBK + kq * 8);
        #pragma unroll
        for (int n = 0; n < 4; ++n)
            bfr[n] = *reinterpret_cast<const bf16x8*>(Bs + (wc * 64 + n * 16 + lr) * FBK + kq * 8);

        #pragma unroll
        for (int m = 0; m < 4; ++m)
            #pragma unroll
            for (int n = 0; n < 4; ++n)
                acc[m][n] = __builtin_amdgcn_mfma_f32_16x16x32_bf16(af[m], bfr[n], acc[m][n], 0, 0, 0);

        __syncthreads();
    }

    const int crow0 = kq * 4;
    #pragma unroll
    for (int n = 0; n < 4; ++n) {
        const int col = bn + wc * 64 + n * 16 + lr;
        const float bv = bias[col];
        #pragma unroll
        for (int m = 0; m < 4; ++m) {
            const int rowb = bm + wr * 64 + m * 16 + crow0;
            #pragma unroll
            for (int j = 0; j < 4; ++j)
                out[(size_t)(rowb + j) * OUT_F + col] = acc[m][n][j] + bv;
        }
    }
}

// ---------------------------------------------------------------------------
extern "C" void kernel_launch(void* const* d_in, const int* in_sizes, int n_in,
                              void* d_out, int out_size, void* d_ws, size_t ws_size,
                              hipStream_t stream) {
    const float* x      = (const float*)d_in[0];
    const float* weight = (const float*)d_in[1];
    const float* bias   = (const float*)d_in[2];
    const float* leafs  = (const float*)d_in[3];
    float* out = (float*)d_out;

    unsigned short* wb = (unsigned short*)d_ws;
    unsigned short* xbuf = (unsigned short*)((char*)d_ws +
                           (size_t)OUT_F * IN_F * sizeof(unsigned short));

    const size_t need_full = (size_t)OUT_F * IN_F * 2 + (size_t)M_ROWS * IN_F * 2;
    const bool full = ws_size >= need_full;

    if (full) {
        prep_kernel<<<dim3(PREP_NBLK), dim3(256), 0, stream>>>(
            weight, leafs, x, wb, xbuf);
        gemm_tlp_kernel<<<dim3((M_ROWS / 256) * (OUT_F / 128)), dim3(512), 0, stream>>>(
            xbuf, wb, bias, out);
    } else {
        prep_kernel<<<dim3(PREP_WBLK), dim3(256), 0, stream>>>(
            weight, leafs, x, wb, xbuf);
        gemm_fb_kernel<<<dim3(M_ROWS / FBM, OUT_F / FBN), dim3(256), 0, stream>>>(
            x, wb, bias, out);
    }
}